// Round 9
// baseline (349.008 us; speedup 1.0000x reference)
//
#include <hip/hip_runtime.h>

typedef __attribute__((ext_vector_type(8))) __bf16 bf16x8;
typedef __attribute__((ext_vector_type(4))) float f32x4;

constexpr int BATCH = 16384;
constexpr int DIN   = 1024;
constexpr int DHID  = 1000;
constexpr int MAXA  = 3129;
constexpr int MBMAX = 131;          // max 128-row m-blocks total (128 + 3 padding)

// A/Hp chunk: [kc(4)][r(128)][e8(8)] bf16 = 8 KB per (m-tile, kt); KT=32 (BK=32)
// B chunk:    [kc(4)][n(256)][e8(8)] bf16 = 16 KB per (n-tile, kt)
constexpr size_t SZ_AP  = (size_t)MBMAX * 32 * 8192;   // 34,340,864
constexpr size_t SZ_HP  = SZ_AP;
constexpr size_t SZ_W1P = (size_t)12 * 32 * 16384;     // 6,291,456  (3e x 4nb)
constexpr size_t SZ_W2P = (size_t)16 * 32 * 16384;     // 8,388,608  (1+2+13 n-tiles)
constexpr size_t WS_HP  = 0;
constexpr size_t WS_W1P = WS_HP + SZ_HP;
constexpr size_t WS_W2P = WS_W1P + SZ_W1P;
constexpr size_t WS_CNT = WS_W2P + SZ_W2P;
constexpr size_t WS_IDX = WS_CNT + 1024;
constexpr size_t WS_AP  = WS_IDX + (size_t)3 * BATCH * 4;
constexpr size_t WS_NEED = WS_AP + SZ_AP;

constexpr int PA_BLK  = 2096;   // 131*32*128/256
constexpr int PW1_BLK = 384;    // 12 tiles x 32 kt
constexpr int PW2_BLK = 512;    // 16 tiles x 32 kt

__device__ __forceinline__ ushort f2bf(float f) {
    return __builtin_bit_cast(ushort, (__bf16)f);
}

__device__ __forceinline__ void gload16(const void* g, void* l) {
    __builtin_amdgcn_global_load_lds((const __attribute__((address_space(1))) void*)g,
                                     (__attribute__((address_space(3))) void*)l, 16, 0, 0);
}

// counts ints: [0..2]=expert counts, [8]=g1 ticket, [12]=g2 ticket
__global__ void zero_k(int* __restrict__ c) { if (threadIdx.x < 16) c[threadIdx.x] = 0; }

__global__ void route_k(const float* __restrict__ qt, int* __restrict__ counts,
                        int* __restrict__ idx) {
    int i = blockIdx.x * 256 + threadIdx.x;
    if (i >= BATCH) return;
    float a = qt[3 * i], b = qt[3 * i + 1], c = qt[3 * i + 2];
    int p = 0; float m = a;
    if (b > m) { m = b; p = 1; }
    if (c > m) { m = c; p = 2; }
    int pos = atomicAdd(&counts[p], 1);
    idx[p * BATCH + pos] = i;
}

// Fused pack: [0,PA) gather+convert A (8KB chunks), then W1, W2 (16KB chunks).
__global__ void pack_all_k(const float* __restrict__ hs,
                           const float* __restrict__ w1_0, const float* __restrict__ w1_1,
                           const float* __restrict__ w1_2,
                           const float* __restrict__ w2_0, const float* __restrict__ w2_1,
                           const float* __restrict__ w2_2,
                           const int* __restrict__ counts, const int* __restrict__ idx,
                           ushort* __restrict__ Ap, ushort* __restrict__ W1p,
                           ushort* __restrict__ W2p) {
    const int b = blockIdx.x, tid = threadIdx.x;
    if (b < PA_BLK) {
        const int g = b * 256 + tid;
        const int m = g & 127, kt = (g >> 7) & 31, mb = g >> 12;
        const int c0 = counts[0], c1 = counts[1], c2 = counts[2];
        const int n0 = (c0 + 127) >> 7, n1 = (c1 + 127) >> 7, n2 = (c2 + 127) >> 7;
        if (mb >= n0 + n1 + n2) return;
        int e = 0, lm = mb, cnt = c0;
        if (lm >= n0) { lm -= n0; e = 1; cnt = c1; }
        if (e == 1 && lm >= n1) { lm -= n1; e = 2; cnt = c2; }
        int ri = lm * 128 + m; if (ri >= cnt) ri = cnt - 1;
        const float* row = hs + (size_t)idx[e * BATCH + ri] * DIN + kt * 32;
        ushort* dst = Ap + (size_t)(mb * 32 + kt) * 4096 + m * 8;
#pragma unroll
        for (int kc = 0; kc < 4; kc++) {
            float4 f0 = *reinterpret_cast<const float4*>(row + kc * 8);
            float4 f1 = *reinterpret_cast<const float4*>(row + kc * 8 + 4);
            union { ushort u[8]; int4 v; } p;
            p.u[0] = f2bf(f0.x); p.u[1] = f2bf(f0.y); p.u[2] = f2bf(f0.z); p.u[3] = f2bf(f0.w);
            p.u[4] = f2bf(f1.x); p.u[5] = f2bf(f1.y); p.u[6] = f2bf(f1.z); p.u[7] = f2bf(f1.w);
            *reinterpret_cast<int4*>(dst + kc * 1024) = p.v;
        }
    } else if (b < PA_BLK + PW1_BLK) {
        const int bb = b - PA_BLK;
        const int kt = bb & 31, tile = bb >> 5;            // tile = e*4 + nbk
        const int e = tile >> 2, nbk = tile & 3;
        const float* W = e == 0 ? w1_0 : e == 1 ? w1_1 : w1_2;
        const int n = nbk * 256 + tid;
        ushort* dst = W1p + (size_t)(tile * 32 + kt) * 8192 + tid * 8;
#pragma unroll
        for (int kc = 0; kc < 4; kc++) {
            union { ushort u[8]; int4 v; } p;
#pragma unroll
            for (int j = 0; j < 8; j++) {
                int k = kt * 32 + kc * 8 + j;
                float f = (n < DHID) ? W[(size_t)k * DHID + n] : 0.f;
                p.u[j] = f2bf(f);
            }
            *reinterpret_cast<int4*>(dst + kc * 2048) = p.v;
        }
    } else {
        const int bb = b - PA_BLK - PW1_BLK;
        const int kt = bb & 31, t = bb >> 5;               // t in [0,16)
        const int e = (t < 1) ? 0 : (t < 3) ? 1 : 2;
        const int nb = t - (e == 0 ? 0 : e == 1 ? 1 : 3);
        const int ne = e == 0 ? 2 : e == 1 ? 482 : MAXA;
        const float* W = e == 0 ? w2_0 : e == 1 ? w2_1 : w2_2;
        const int nn = nb * 256 + tid;
        ushort* dst = W2p + (size_t)(t * 32 + kt) * 8192 + tid * 8;
#pragma unroll
        for (int kc = 0; kc < 4; kc++) {
            union { ushort u[8]; int4 v; } p;
#pragma unroll
            for (int j = 0; j < 8; j++) {
                int k = kt * 32 + kc * 8 + j;
                float f = (k < DHID && nn < ne) ? W[(size_t)k * ne + nn] : 0.f;
                p.u[j] = f2bf(f);
            }
            *reinterpret_cast<int4*>(dst + kc * 2048) = p.v;
        }
    }
}

// ---- 128x256 K-loop: triple-buffered (24KB bufs), counted vmcnt(6), 1 barrier/step ----
#define STAGE6(BUFO, KT)                                                        \
    {                                                                           \
        const char* as_ = Ag + (size_t)(KT) * 8192 + tid * 16;                  \
        char* ad_ = lds + (BUFO) + w * 1024;                                    \
        gload16(as_, ad_);                                                      \
        gload16(as_ + 4096, ad_ + 4096);                                        \
        const char* bs_ = Bg + (size_t)(KT) * 16384 + tid * 16;                 \
        char* bd_ = lds + (BUFO) + 8192 + w * 1024;                             \
        gload16(bs_, bd_);                                                      \
        gload16(bs_ + 4096, bd_ + 4096);                                        \
        gload16(bs_ + 8192, bd_ + 8192);                                        \
        gload16(bs_ + 12288, bd_ + 12288);                                      \
    }

#define KLOOP256()                                                              \
    f32x4 acc[4][8] = {};                                                       \
    STAGE6(0, 0)                                                                \
    STAGE6(24576, 1)                                                            \
    {                                                                           \
        int cur = 0;                                                            \
        for (int kt = 0; kt < 32; ++kt) {                                       \
            if (kt < 31) asm volatile("s_waitcnt vmcnt(6)" ::: "memory");       \
            else         asm volatile("s_waitcnt vmcnt(0)" ::: "memory");       \
            asm volatile("s_barrier" ::: "memory");                             \
            if (kt + 2 < 32) {                                                  \
                int nx = cur + 2; if (nx >= 3) nx -= 3;                         \
                STAGE6(nx * 24576, kt + 2)                                      \
            }                                                                   \
            const char* base = lds + cur * 24576;                               \
            bf16x8 af[4], bfr[8];                                               \
            _Pragma("unroll")                                                   \
            for (int mi = 0; mi < 4; mi++)                                      \
                af[mi] = *reinterpret_cast<const bf16x8*>(                      \
                    base + kq4 * 2048 + (wm * 64 + mi * 16 + l15) * 16);        \
            _Pragma("unroll")                                                   \
            for (int ni = 0; ni < 8; ni++)                                      \
                bfr[ni] = *reinterpret_cast<const bf16x8*>(                     \
                    base + 8192 + kq4 * 4096 + (wn * 128 + ni * 16 + l15) * 16);\
            __builtin_amdgcn_s_setprio(1);                                      \
            _Pragma("unroll")                                                   \
            for (int mi = 0; mi < 4; mi++)                                      \
                _Pragma("unroll")                                               \
                for (int ni = 0; ni < 8; ni++)                                  \
                    acc[mi][ni] = __builtin_amdgcn_mfma_f32_16x16x32_bf16(      \
                        af[mi], bfr[ni], acc[mi][ni], 0, 0, 0);                 \
            __builtin_amdgcn_s_setprio(0);                                      \
            cur = cur + 1; if (cur == 3) cur = 0;                               \
        }                                                                       \
    }                                                                           \
    asm volatile("s_barrier" ::: "memory");

// ---------------- GEMM1 (work-stealing): Hp = tanh(Ap @ W1p + b1) -------------
__global__ __launch_bounds__(256, 2)
void gemm1_k(const char* __restrict__ ApB, const char* __restrict__ W1pB,
             const float* __restrict__ b1_0, const float* __restrict__ b1_1,
             const float* __restrict__ b1_2,
             const int* __restrict__ counts, int* __restrict__ wq,
             char* __restrict__ HpB) {
    __shared__ __align__(16) char lds[73728];
    __shared__ int s_t;
    const int c0 = counts[0], c1 = counts[1], c2 = counts[2];
    const int n0 = (c0 + 127) >> 7, n1 = (c1 + 127) >> 7, n2 = (c2 + 127) >> 7;
    const int T = (n0 + n1 + n2) * 4;

    const int tid = threadIdx.x;
    const int lane = tid & 63, w = tid >> 6, wm = w >> 1, wn = w & 1;
    const int l15 = lane & 15, kq4 = lane >> 4;

    for (;;) {
        if (tid == 0) s_t = atomicAdd(wq, 1);
        __syncthreads();
        const int t = s_t;
        if (t >= T) break;

        const int mbG = t >> 2, nbk = t & 3;
        int e = 0, lm = mbG;
        if (lm >= n0) { lm -= n0; e = 1; }
        if (e == 1 && lm >= n1) { lm -= n1; e = 2; }
        const float* bias = e == 0 ? b1_0 : e == 1 ? b1_1 : b1_2;
        const char* Ag = ApB + (size_t)mbG * (32 * 8192);
        const char* Bg = W1pB + (size_t)((e * 4 + nbk) * 32) * 16384;

        KLOOP256()

        // epilogue: build 64KB Hp image (8 chunks) in LDS, then int4 copy-out
        ushort* img = (ushort*)lds;
#pragma unroll
        for (int mi = 0; mi < 4; mi++) {
            const int rb = wm * 64 + mi * 16 + kq4 * 4;
#pragma unroll
            for (int ni = 0; ni < 8; ni++) {
                const int nl = wn * 128 + ni * 16 + l15;
                const int ng = nbk * 256 + nl;
                const bool live = ng < DHID;
                const float bv = live ? bias[ng] : 0.f;
                const int ua = (nl >> 5) * 4096 + ((nl >> 3) & 3) * 1024 + (nl & 6);
#pragma unroll
                for (int rg = 0; rg < 4; rg++) {
                    float vv = live ? tanhf(acc[mi][ni][rg] + bv) : 0.f;
                    float vo = __shfl_xor(vv, 1);
                    ushort lo = (l15 & 1) ? f2bf(vo) : f2bf(vv);
                    ushort hi = (l15 & 1) ? f2bf(vv) : f2bf(vo);
                    *reinterpret_cast<uint*>(img + ua + (rb + rg) * 8) =
                        (uint)lo | ((uint)hi << 16);
                }
            }
        }
        asm volatile("s_barrier" ::: "memory");
        char* hdst = HpB + ((size_t)mbG * 32 + nbk * 8) * 8192;
#pragma unroll
        for (int i2 = 0; i2 < 16; i2++) {
            const int s = tid + i2 * 256;
            *reinterpret_cast<int4*>(hdst + s * 16) =
                *reinterpret_cast<const int4*>(lds + s * 16);
        }
        asm volatile("s_barrier" ::: "memory");
    }
}

// ---------------- GEMM2 (work-stealing): Out = Hp @ W2p + b2 ------------------
__global__ __launch_bounds__(256, 2)
void gemm2_k(const char* __restrict__ HpB, const char* __restrict__ W2pB,
             const float* __restrict__ b2_0, const float* __restrict__ b2_1,
             const float* __restrict__ b2_2,
             const int* __restrict__ counts, const int* __restrict__ idx,
             int* __restrict__ wq, int fallback, float* __restrict__ Out) {
    __shared__ __align__(16) char lds[73728];
    __shared__ int s_t;
    const int c0 = counts[0], c1 = counts[1], c2 = counts[2];
    int nb[3]  = {(c0 + 127) >> 7, (c1 + 127) >> 7, (c2 + 127) >> 7};
    int cc[3]  = {c0, c1, c2};
    const int nbn[3]  = {1, 2, 13};
    const int nz[3]   = {23, 21, 0};
    const int zst[3]  = {256, 512, 0};
    const int toff[3] = {0, 1, 3};
    const int nel[3]  = {2, 482, MAXA};
    const int Tc = nb[0] * 1 + nb[1] * 2 + nb[2] * 13;
    const int Tz = fallback ? (nb[0] * 23 + nb[1] * 21) : 0;
    const int T = Tc + Tz;

    const int tid = threadIdx.x;
    const int lane = tid & 63, w = tid >> 6, wm = w >> 1, wn = w & 1;
    const int l15 = lane & 15, kq4 = lane >> 4;

    for (;;) {
        if (tid == 0) s_t = atomicAdd(wq, 1);
        __syncthreads();
        const int t = s_t;
        if (t >= T) break;

        if (t < Tc) {
            int e = 0, r = t, mbG = 0;
            while (e < 2 && r >= nb[e] * nbn[e]) { r -= nb[e] * nbn[e]; mbG += nb[e]; ++e; }
            const int lm = r / nbn[e], nbk = r - lm * nbn[e];
            mbG += lm;
            const int cnt = cc[e], ne = nel[e];
            const float* bias = e == 0 ? b2_0 : e == 1 ? b2_1 : b2_2;
            const char* Ag = HpB + (size_t)mbG * (32 * 8192);
            const char* Bg = W2pB + (size_t)((toff[e] + nbk) * 32) * 16384;

            KLOOP256()

            // epilogue: 2-pass f32 bounce (64 rows x stride 260), float4 stores
            const int m0 = lm * 128;
            float* bf32 = (float*)lds;
            const int* ip = idx + e * BATCH;
#pragma unroll
            for (int h = 0; h < 2; h++) {
                if (wm == h) {
#pragma unroll
                    for (int mi = 0; mi < 4; mi++) {
                        const int rl = mi * 16 + kq4 * 4;
#pragma unroll
                        for (int ni = 0; ni < 8; ni++) {
                            const int nl = wn * 128 + ni * 16 + l15;
                            const int ncol = nbk * 256 + nl;
                            const bool live = ncol < ne;
                            const float bv = live ? bias[ncol] : 0.f;
#pragma unroll
                            for (int rg = 0; rg < 4; rg++)
                                bf32[(rl + rg) * 260 + nl] =
                                    live ? (acc[mi][ni][rg] + bv) : 0.f;
                        }
                    }
                }
                asm volatile("s_barrier" ::: "memory");
#pragma unroll
                for (int i2 = 0; i2 < 16; i2++) {
                    const int s = tid + i2 * 256;
                    const int rr = s >> 6, c4 = s & 63;
                    const int mrow = m0 + h * 64 + rr;
                    const int ncol0 = nbk * 256 + c4 * 4;
                    if (mrow < cnt && ncol0 < MAXA && (ncol0 < ne || fallback)) {
                        const int orow = ip[mrow];
                        float4 val = *reinterpret_cast<const float4*>(bf32 + rr * 260 + c4 * 4);
                        float* op = Out + (size_t)orow * MAXA + ncol0;
                        if (ncol0 + 3 < MAXA) {
                            *reinterpret_cast<float4*>(op) = val;
                        } else {
                            if (ncol0 + 0 < MAXA) op[0] = val.x;
                            if (ncol0 + 1 < MAXA) op[1] = val.y;
                            if (ncol0 + 2 < MAXA) op[2] = val.z;
                        }
                    }
                }
                asm volatile("s_barrier" ::: "memory");
            }
        } else {
            // zero tiles (fallback mode only: Ap aliases d_out tail)
            int e = 0, r = t - Tc;
            while (e < 2 && r >= nb[e] * nz[e]) { r -= nb[e] * nz[e]; ++e; }
            const int lm = r / nz[e], zc = r - lm * nz[e];
            const int cnt = cc[e];
            const int col0 = zst[e] + zc * 128;
            const int width = (MAXA - col0 < 128) ? (MAXA - col0) : 128;
            const int m0 = lm * 128;
            const int nrow = (cnt - m0 < 128) ? (cnt - m0) : 128;
            const int* rowp = idx + e * BATCH + m0;
            const float4 z4 = {0.f, 0.f, 0.f, 0.f};
            if (width == 128) {
                for (int s = tid; s < (nrow << 5); s += 256) {
                    const int rl = s >> 5, c4 = s & 31;
                    *reinterpret_cast<float4*>(Out + (size_t)rowp[rl] * MAXA + col0 + c4 * 4) = z4;
                }
            } else {
                const int f4 = width >> 2;
                for (int s = tid; s < nrow * f4; s += 256) {
                    const int rl = s / f4, c4 = s - rl * f4;
                    *reinterpret_cast<float4*>(Out + (size_t)rowp[rl] * MAXA + col0 + c4 * 4) = z4;
                }
                const int rem = width & 3;
                for (int s = tid; s < nrow * rem; s += 256) {
                    const int rl = s / rem, j = s - rl * rem;
                    Out[(size_t)rowp[rl] * MAXA + col0 + f4 * 4 + j] = 0.f;
                }
            }
            __syncthreads();
        }
    }
}

extern "C" void kernel_launch(void* const* d_in, const int* in_sizes, int n_in,
                              void* d_out, int out_size, void* d_ws, size_t ws_size,
                              hipStream_t stream) {
    const float* hs = (const float*)d_in[0];
    const float* qt = (const float*)d_in[1];
    const float* w1_0 = (const float*)d_in[2],  *b1_0 = (const float*)d_in[3];
    const float* w2_0 = (const float*)d_in[4],  *b2_0 = (const float*)d_in[5];
    const float* w1_1 = (const float*)d_in[6],  *b1_1 = (const float*)d_in[7];
    const float* w2_1 = (const float*)d_in[8],  *b2_1 = (const float*)d_in[9];
    const float* w1_2 = (const float*)d_in[10], *b1_2 = (const float*)d_in[11];
    const float* w2_2 = (const float*)d_in[12], *b2_2 = (const float*)d_in[13];

    char* ws = (char*)d_ws;
    ushort* Hp  = (ushort*)(ws + WS_HP);
    ushort* W1p = (ushort*)(ws + WS_W1P);
    ushort* W2p = (ushort*)(ws + WS_W2P);
    int* counts = (int*)(ws + WS_CNT);
    int* idx    = (int*)(ws + WS_IDX);
    const int fallback = (ws_size >= WS_NEED) ? 0 : 1;
    ushort* Ap = fallback ? (ushort*)((char*)d_out + ((size_t)out_size * 4 - SZ_AP))
                          : (ushort*)(ws + WS_AP);
    float* Out = (float*)d_out;

    zero_k<<<1, 64, 0, stream>>>(counts);
    route_k<<<64, 256, 0, stream>>>(qt, counts, idx);
    pack_all_k<<<PA_BLK + PW1_BLK + PW2_BLK, 256, 0, stream>>>(
        hs, w1_0, w1_1, w1_2, w2_0, w2_1, w2_2, counts, idx, Ap, W1p, W2p);
    gemm1_k<<<512, 256, 0, stream>>>((const char*)Ap, (const char*)W1p,
                                     b1_0, b1_1, b1_2, counts, counts + 8, (char*)Hp);
    gemm2_k<<<512, 256, 0, stream>>>((const char*)Hp, (const char*)W2p,
                                     b2_0, b2_1, b2_2, counts, idx, counts + 12,
                                     fallback, Out);
}